// Round 1
// 79.093 us; speedup vs baseline: 1.0584x; 1.0584x over previous
//
#include <hip/hip_runtime.h>
#include <cstdint>

// Ball query: B=8, N=4096, radius=0.2, nsample=32. Queries == sources.
// Output int32 (B,N,32): first 32 in-radius indices ascending, padded with
// the first match.
//
// NUMERICS (LOCKED, R8-verified absmax=0): expansion form f32,
//   sq  = (x*x + y*y) + z*z              -- plain, no FMA
//   dot = fma(qz,sz, fma(qy,sy, qx*sx))  -- FMA, K ascending
//   d2  = (sqq + sqs) - (dot + dot)
//   match = d2 < 0.04f
// All in inline asm -- immune to -ffast-math/contract. DO NOT CHANGE.
//
// R12 perf theory: R11 wall (~41us kernel; dur 83.7 = 41.4 harness fill +
// kernel) was NOT occupancy-bound (R10->R11 occupancy 2x: no change).
// Residual over VALU(16.6us)+LDS(9us) was structural: 3 block barriers +
// forced restage on every block, zero block backlog (1024 blocks = exactly
// resident -> corner-query tail stalls CUs), and emit's 6-dependent-shfl
// prefix chain. R12: global-direct scan -- input is 48KB/batch (L2-resident,
// 768B/wave coalesced loads), so LDS staging/barriers are pure overhead.
//  * no LDS, no __syncthreads; sq recomputed per shared round (same asm)
//  * 4096 blocks x 128 thr (4 queries/wave, 2 cascades) -> 8192 independent
//    waves, ~2x backlog for dynamic balance of full-scan corner queries
//  * prefix-free emit: capture wpre (= running count before round k) at
//    lane==k during scan; emit is pure stores, no shfl_up chain.

#define BQ_N    4096
#define BQ_B    8
#define BQ_NS   32
#define BQ_R2   0.04f

__device__ __forceinline__ float sq_plain(float x, float y, float z) {
    float r, t;
    asm("v_mul_f32 %0, %2, %2\n\t"
        "v_mul_f32 %1, %3, %3\n\t"
        "v_add_f32 %0, %0, %1\n\t"
        "v_mul_f32 %1, %4, %4\n\t"
        "v_add_f32 %0, %0, %1"
        : "=&v"(r), "=&v"(t)
        : "v"(x), "v"(y), "v"(z));
    return r;
}

__device__ __forceinline__ float d2_mixed(float qx, float qy, float qz, float sqq,
                                          float sx, float sy, float sz, float sqs) {
    float r, t;
    asm("v_mul_f32 %0, %2, %5\n\t"     // qx*sx
        "v_fma_f32 %0, %3, %6, %0\n\t" // + qy*sy (fused)
        "v_fma_f32 %0, %4, %7, %0\n\t" // + qz*sz (fused) = dot
        "v_add_f32 %0, %0, %0\n\t"     // 2*dot (exact)
        "v_add_f32 %1, %8, %9\n\t"     // sqq + sqs
        "v_sub_f32 %0, %1, %0"         // d2
        : "=&v"(r), "=&v"(t)
        : "v"(qx), "v"(qy), "v"(qz), "v"(sx), "v"(sy), "v"(sz),
          "v"(sqq), "v"(sqs));
    return r;
}

// One 4-round chunk (256 points) for a single query, points straight from
// global (L2-hit: 48KB/batch is L2-resident). Captures per-round ballot word
// AND the exclusive prefix count (wpre) at lane==k -- emit needs no scan.
__device__ __forceinline__ void scan1g(const float* __restrict__ src, int lane,
                                       const float4& q, int c,
                                       uint64_t& word, int& wpre, int& found) {
    float X[4], Y[4], Z[4];
    #pragma unroll
    for (int u = 0; u < 4; ++u) {           // 4 independent 768B/wave loads
        const int k = (c << 2) + u;
        const float* ptr = src + (size_t)(((k << 6) + lane) * 3);
        X[u] = ptr[0]; Y[u] = ptr[1]; Z[u] = ptr[2];
    }
    #pragma unroll
    for (int u = 0; u < 4; ++u) {
        const int k = (c << 2) + u;
        const float sqs = sq_plain(X[u], Y[u], Z[u]);
        const float d2  = d2_mixed(q.x, q.y, q.z, q.w, X[u], Y[u], Z[u], sqs);
        const uint64_t bal = __ballot(d2 < BQ_R2);
        if (lane == k) { word = bal; wpre = found; }
        found += (int)__popcll(bal);
    }
}

// Dual-query cascade over chunk range [c0, c1): both share each global load
// and the shared sq; after the OR-break, singles finish independently.
__device__ __forceinline__ void scan2g(const float* __restrict__ src, int lane,
                                       const float4& q0, const float4& q1,
                                       int c0, int c1,
                                       uint64_t& w0, uint64_t& w1,
                                       int& p0, int& p1, int& f0, int& f1) {
    int c = c0;
    while (c < c1) {
        float X[4], Y[4], Z[4];
        #pragma unroll
        for (int u = 0; u < 4; ++u) {
            const int k = (c << 2) + u;
            const float* ptr = src + (size_t)(((k << 6) + lane) * 3);
            X[u] = ptr[0]; Y[u] = ptr[1]; Z[u] = ptr[2];
        }
        #pragma unroll
        for (int u = 0; u < 4; ++u) {
            const int k = (c << 2) + u;
            const float sqs = sq_plain(X[u], Y[u], Z[u]);
            const float d20 = d2_mixed(q0.x, q0.y, q0.z, q0.w,
                                       X[u], Y[u], Z[u], sqs);
            const float d21 = d2_mixed(q1.x, q1.y, q1.z, q1.w,
                                       X[u], Y[u], Z[u], sqs);
            const uint64_t b0 = __ballot(d20 < BQ_R2);
            const uint64_t b1 = __ballot(d21 < BQ_R2);
            if (lane == k) { w0 = b0; w1 = b1; p0 = f0; p1 = f1; }
            f0 += (int)__popcll(b0);
            f1 += (int)__popcll(b1);
        }
        ++c;
        if (f0 >= BQ_NS || f1 >= BQ_NS) break;   // uniform
    }
    for (int ca = c; ca < c1 && f0 < BQ_NS; ++ca) scan1g(src, lane, q0, ca, w0, p0, f0);
    for (int cb = c; cb < c1 && f1 < BQ_NS; ++cb) scan1g(src, lane, q1, cb, w1, p1, f1);
}

// Prefix-free emit: lane k holds round-k word and wpre (= matches before
// round k, captured during scan). Pure stores; padding only when total<32.
__device__ __forceinline__ void emit_query(int* __restrict__ orow, int lane,
                                           uint64_t word, int wpre, int total) {
    uint64_t w = word;
    int pos = wpre;                      // >=32 for overshoot rounds -> skipped
    while (w != 0ull && pos < BQ_NS) {
        const int bit = __builtin_ctzll(w);
        orow[pos] = (lane << 6) + bit;   // lane == round k; ascending order
        w &= (w - 1);
        ++pos;
    }
    if (total < BQ_NS) {                 // rare (queries with <32 neighbors)
        int first;
        const uint64_t nz = __ballot(word != 0ull);
        if (nz == 0ull) {
            first = BQ_N;   // defensive; self-match (|d2|<=2e-7) makes this unreachable
        } else {
            const int fl = __builtin_ctzll(nz);
            const uint64_t fw = __shfl(word, fl);
            first = (fl << 6) + __builtin_ctzll(fw);
        }
        if (lane >= total && lane < BQ_NS) orow[lane] = first;
    }
}

__global__ __launch_bounds__(128, 4)
void ball_query_kernel(const float* __restrict__ xyz, int* __restrict__ out)
{
    const int b     = blockIdx.x >> 9;          // 512 blocks per batch
    const int qbase = (blockIdx.x & 511) << 3;  // 8 queries per block
    const int lane  = threadIdx.x & 63;
    const int wid   = threadIdx.x >> 6;         // 2 independent waves/block
    const float* __restrict__ src = xyz + (size_t)b * BQ_N * 3;
    int* __restrict__ outb = out + (size_t)(b * BQ_N) * BQ_NS;

    // Wave's 4 query points (wave-uniform addresses -> scalar/L2).
    float4 Q[4];
    #pragma unroll
    for (int j = 0; j < 4; ++j) {
        const int m = qbase + (wid << 2) + j;
        const float x = src[3 * m + 0];
        const float y = src[3 * m + 1];
        const float z = src[3 * m + 2];
        Q[j] = make_float4(x, y, z, sq_plain(x, y, z));
    }

    uint64_t W[4] = {0, 0, 0, 0};
    int      P[4] = {0, 0, 0, 0};
    int      F[4] = {0, 0, 0, 0};

    // Two cascades over all 16 chunks (4096 points), no phases, no barriers.
    scan2g(src, lane, Q[0], Q[1], 0, 16, W[0], W[1], P[0], P[1], F[0], F[1]);
    scan2g(src, lane, Q[2], Q[3], 0, 16, W[2], W[3], P[2], P[3], F[2], F[3]);

    #pragma unroll
    for (int j = 0; j < 4; ++j) {
        const int m = qbase + (wid << 2) + j;
        emit_query(outb + (size_t)m * BQ_NS, lane, W[j], P[j], F[j]);
    }
}

extern "C" void kernel_launch(void* const* d_in, const int* in_sizes, int n_in,
                              void* d_out, int out_size, void* d_ws, size_t ws_size,
                              hipStream_t stream)
{
    const float* xyz = (const float*)d_in[0];   // (8, 4096, 3) f32; d_in[1] unused
    int* out = (int*)d_out;                     // (8, 4096, 32) int32
    hipLaunchKernelGGL(ball_query_kernel, dim3(4096), dim3(128), 0, stream,
                       xyz, out);
}